// Round 7
// baseline (124.731 us; speedup 1.0000x reference)
//
#include <hip/hip_runtime.h>
#include <stdint.h>

// ScatterND (k=1): out = data.copy(); out[indices[i]] = updates[i]
// data: [1000000,64] f32   indices: [100000,1] i32   updates: [100000,64] f32
//
// R7: single-pass fused gather (R4 structure) WITHOUT nontemporal hints
// (R6 proved nt costs ~8 us) and with a fast custom perm-clear kernel
// (replaces the runtime's slow 27 GB/s fill path).
//   1. zero_perm:    perm[row] = -1                 (4 MB write)
//   2. scatter_perm: perm[idx[i]] = i               (0.4 MB random write)
//   3. fused:        out = gather(perm ? upd : data) -- out written once,
//      sequentially; minimal traffic ~516 MB.

typedef float f32x4 __attribute__((ext_vector_type(4)));
typedef int   i32x4 __attribute__((ext_vector_type(4)));

__global__ __launch_bounds__(256) void zero_perm_kernel(i32x4* __restrict__ p,
                                                        size_t n4) {
    size_t i = (size_t)blockIdx.x * blockDim.x + threadIdx.x;
    const size_t stride = (size_t)gridDim.x * blockDim.x;
    const i32x4 m1 = {-1, -1, -1, -1};
    for (; i < n4; i += stride) p[i] = m1;
}

__global__ __launch_bounds__(256) void scatter_perm_kernel(
    const int* __restrict__ idx, int* __restrict__ perm, int n) {
    int t = blockIdx.x * blockDim.x + threadIdx.x;
    if (t < n) perm[idx[t]] = t;
}

__global__ __launch_bounds__(256) void fused_write_kernel(
    const f32x4* __restrict__ data,
    const f32x4* __restrict__ upd,
    const int* __restrict__ perm,
    f32x4* __restrict__ out,
    size_t n4) {
    const size_t stride = (size_t)gridDim.x * blockDim.x;
    size_t i = (size_t)blockIdx.x * blockDim.x + threadIdx.x;

    for (; i + 3 * stride < n4; i += 4 * stride) {
        const size_t i0 = i, i1 = i + stride, i2 = i + 2 * stride, i3 = i + 3 * stride;
        const int j0 = perm[i0 >> 4];
        const int j1 = perm[i1 >> 4];
        const int j2 = perm[i2 >> 4];
        const int j3 = perm[i3 >> 4];
        // Per-lane pointer select: single load path, no exec-mask divergence.
        const f32x4* s0 = (j0 >= 0) ? (upd + ((size_t)j0 * 16 + (i0 & 15))) : (data + i0);
        const f32x4* s1 = (j1 >= 0) ? (upd + ((size_t)j1 * 16 + (i1 & 15))) : (data + i1);
        const f32x4* s2 = (j2 >= 0) ? (upd + ((size_t)j2 * 16 + (i2 & 15))) : (data + i2);
        const f32x4* s3 = (j3 >= 0) ? (upd + ((size_t)j3 * 16 + (i3 & 15))) : (data + i3);
        f32x4 v0 = *s0;
        f32x4 v1 = *s1;
        f32x4 v2 = *s2;
        f32x4 v3 = *s3;
        out[i0] = v0;
        out[i1] = v1;
        out[i2] = v2;
        out[i3] = v3;
    }
    for (; i < n4; i += stride) {
        const int j = perm[i >> 4];
        const f32x4* s = (j >= 0) ? (upd + ((size_t)j * 16 + (i & 15))) : (data + i);
        out[i] = *s;
    }
}

// Fallback (ws too small): plain copy then scatter.
__global__ __launch_bounds__(256) void copy_all_kernel(
    const f32x4* __restrict__ src, f32x4* __restrict__ dst, size_t n4) {
    size_t i = (size_t)blockIdx.x * blockDim.x + threadIdx.x;
    const size_t stride = (size_t)gridDim.x * blockDim.x;
    for (; i < n4; i += stride) dst[i] = src[i];
}

__global__ __launch_bounds__(256) void scatter_kernel(
    const int* __restrict__ idx, const f32x4* __restrict__ upd,
    f32x4* __restrict__ out, size_t total4) {
    size_t i = (size_t)blockIdx.x * blockDim.x + threadIdx.x;
    const size_t stride = (size_t)gridDim.x * blockDim.x;
    for (; i < total4; i += stride) {
        const size_t row = i >> 4;
        const size_t col = i & 15;
        const int r = idx[row];
        out[(size_t)r * 16 + col] = upd[i];
    }
}

extern "C" void kernel_launch(void* const* d_in, const int* in_sizes, int n_in,
                              void* d_out, int out_size, void* d_ws, size_t ws_size,
                              hipStream_t stream) {
    const float* data    = (const float*)d_in[0];
    const int*   indices = (const int*)d_in[1];
    const float* updates = (const float*)d_in[2];
    float* out = (float*)d_out;

    const size_t n4          = (size_t)out_size / 4;      // 16M float4
    const size_t num_rows    = (size_t)out_size / 64;     // 1,000,000
    const size_t num_updates = (size_t)in_sizes[2] / 64;  // 100,000

    const int block = 256;
    auto grid_for = [&](size_t work) {
        size_t g = (work + block - 1) / block;
        if (g > 2048) g = 2048;
        return (int)g;
    };

    if (ws_size >= num_rows * sizeof(int) && (num_rows % 4) == 0) {
        int* perm = (int*)d_ws;
        zero_perm_kernel<<<grid_for(num_rows / 4), block, 0, stream>>>(
            (i32x4*)perm, num_rows / 4);
        scatter_perm_kernel<<<grid_for(num_updates), block, 0, stream>>>(
            indices, perm, (int)num_updates);
        fused_write_kernel<<<grid_for(n4 / 4), block, 0, stream>>>(
            (const f32x4*)data, (const f32x4*)updates, perm, (f32x4*)out, n4);
    } else {
        const size_t total4 = num_updates * 16;
        copy_all_kernel<<<grid_for(n4), block, 0, stream>>>(
            (const f32x4*)data, (f32x4*)out, n4);
        scatter_kernel<<<grid_for(total4), block, 0, stream>>>(
            indices, (const f32x4*)updates, (f32x4*)out, total4);
    }
}

// Round 8
// 99.879 us; speedup vs baseline: 1.2488x; 1.2488x over previous
//
#include <hip/hip_runtime.h>
#include <stdint.h>

// ScatterND (k=1): out = data.copy(); out[indices[i]] = updates[i]
// data: [1000000,64] f32   indices: [100000,1] i32   updates: [100000,64] f32
//
// R8: flat (loop-free) copy -- one float4 per thread, maximal grid --
// replicating the structure of the runtime fill kernel that sustains
// 7.2 TB/s write-only on this rig (8 VGPRs, no loop-carried state).
// Scatter likewise flat. Tests whether the 2048-block grid-stride loop
// was what pinned all prior copies at ~5 TB/s.

typedef float f32x4 __attribute__((ext_vector_type(4)));

__global__ __launch_bounds__(256) void copy_flat_kernel(
    const f32x4* __restrict__ src, f32x4* __restrict__ dst, size_t n4) {
    const size_t i = (size_t)blockIdx.x * blockDim.x + threadIdx.x;
    if (i < n4) dst[i] = src[i];
}

__global__ __launch_bounds__(256) void scatter_flat_kernel(
    const int* __restrict__ idx,
    const f32x4* __restrict__ upd,
    f32x4* __restrict__ out,
    size_t total4) {
    const size_t i = (size_t)blockIdx.x * blockDim.x + threadIdx.x;
    if (i < total4) {
        const size_t row = i >> 4;
        const size_t col = i & 15;
        const int r = idx[row];
        out[(size_t)r * 16 + col] = upd[i];
    }
}

extern "C" void kernel_launch(void* const* d_in, const int* in_sizes, int n_in,
                              void* d_out, int out_size, void* d_ws, size_t ws_size,
                              hipStream_t stream) {
    const float* data    = (const float*)d_in[0];
    const int*   indices = (const int*)d_in[1];
    const float* updates = (const float*)d_in[2];
    float* out = (float*)d_out;

    const size_t n4          = (size_t)out_size / 4;      // 16M float4
    const size_t num_updates = (size_t)in_sizes[2] / 64;  // 100,000
    const size_t total4      = num_updates * 16;          // 1.6M float4

    const int block = 256;
    const int gc = (int)((n4 + block - 1) / block);       // 65536 blocks
    const int gs = (int)((total4 + block - 1) / block);   // 6250 blocks

    copy_flat_kernel<<<gc, block, 0, stream>>>(
        (const f32x4*)data, (f32x4*)out, n4);
    scatter_flat_kernel<<<gs, block, 0, stream>>>(
        indices, (const f32x4*)updates, (f32x4*)out, total4);
}

// Round 9
// 99.201 us; speedup vs baseline: 1.2574x; 1.0068x over previous
//
#include <hip/hip_runtime.h>
#include <stdint.h>

// ScatterND (k=1): out = data.copy(); out[indices[i]] = updates[i]
// data: [1000000,64] f32   indices: [100000,1] i32   updates: [100000,64] f32
//
// R9: R8's flat loop-free structure (WIN: 114->100 us) + skip-copy of the
// 100k overwritten rows (saves ~51 MB of the 564 MB total).
//   1. zero_flags   (flat, 1 MB)
//   2. scatter_flag (flat, writes update rows + flag bytes)
//   3. copy_skip    (flat, copies data rows where flag==0)

typedef float f32x4 __attribute__((ext_vector_type(4)));
typedef uint32_t u32x4 __attribute__((ext_vector_type(4)));

__global__ __launch_bounds__(256) void zero_flags_kernel(
    u32x4* __restrict__ p, size_t n16) {
    const size_t i = (size_t)blockIdx.x * blockDim.x + threadIdx.x;
    if (i < n16) p[i] = (u32x4){0u, 0u, 0u, 0u};
}

__global__ __launch_bounds__(256) void scatter_flag_kernel(
    const int* __restrict__ idx,
    const f32x4* __restrict__ upd,
    f32x4* __restrict__ out,
    uint8_t* __restrict__ flags,
    size_t total4) {
    const size_t i = (size_t)blockIdx.x * blockDim.x + threadIdx.x;
    if (i < total4) {
        const size_t row = i >> 4;
        const size_t col = i & 15;
        const int r = idx[row];
        out[(size_t)r * 16 + col] = upd[i];
        if (col == 0) flags[r] = 1;
    }
}

__global__ __launch_bounds__(256) void copy_skip_kernel(
    const f32x4* __restrict__ src,
    f32x4* __restrict__ dst,
    const uint8_t* __restrict__ flags,
    size_t n4) {
    const size_t i = (size_t)blockIdx.x * blockDim.x + threadIdx.x;
    if (i < n4 && !flags[i >> 4]) dst[i] = src[i];
}

// Fallback (ws too small): R8's plain flat copy + scatter.
__global__ __launch_bounds__(256) void copy_flat_kernel(
    const f32x4* __restrict__ src, f32x4* __restrict__ dst, size_t n4) {
    const size_t i = (size_t)blockIdx.x * blockDim.x + threadIdx.x;
    if (i < n4) dst[i] = src[i];
}

__global__ __launch_bounds__(256) void scatter_flat_kernel(
    const int* __restrict__ idx,
    const f32x4* __restrict__ upd,
    f32x4* __restrict__ out,
    size_t total4) {
    const size_t i = (size_t)blockIdx.x * blockDim.x + threadIdx.x;
    if (i < total4) {
        const size_t row = i >> 4;
        const size_t col = i & 15;
        const int r = idx[row];
        out[(size_t)r * 16 + col] = upd[i];
    }
}

extern "C" void kernel_launch(void* const* d_in, const int* in_sizes, int n_in,
                              void* d_out, int out_size, void* d_ws, size_t ws_size,
                              hipStream_t stream) {
    const float* data    = (const float*)d_in[0];
    const int*   indices = (const int*)d_in[1];
    const float* updates = (const float*)d_in[2];
    float* out = (float*)d_out;

    const size_t n4          = (size_t)out_size / 4;      // 16M float4
    const size_t num_rows    = (size_t)out_size / 64;     // 1,000,000
    const size_t num_updates = (size_t)in_sizes[2] / 64;  // 100,000
    const size_t total4      = num_updates * 16;          // 1.6M float4

    const int block = 256;
    auto blocks_for = [&](size_t work) {
        return (int)((work + block - 1) / block);
    };

    if (ws_size >= num_rows && (num_rows % 16) == 0) {
        uint8_t* flags = (uint8_t*)d_ws;
        const size_t n16 = num_rows / 16;
        zero_flags_kernel<<<blocks_for(n16), block, 0, stream>>>(
            (u32x4*)flags, n16);
        scatter_flag_kernel<<<blocks_for(total4), block, 0, stream>>>(
            indices, (const f32x4*)updates, (f32x4*)out, flags, total4);
        copy_skip_kernel<<<blocks_for(n4), block, 0, stream>>>(
            (const f32x4*)data, (f32x4*)out, flags, n4);
    } else {
        copy_flat_kernel<<<blocks_for(n4), block, 0, stream>>>(
            (const f32x4*)data, (f32x4*)out, n4);
        scatter_flat_kernel<<<blocks_for(total4), block, 0, stream>>>(
            indices, (const f32x4*)updates, (f32x4*)out, total4);
    }
}

// Round 10
// 98.745 us; speedup vs baseline: 1.2632x; 1.0046x over previous
//
#include <hip/hip_runtime.h>
#include <stdint.h>

// ScatterND (k=1): out = data.copy(); out[indices[i]] = updates[i]
// data: [1000000,64] f32   indices: [100000,1] i32   updates: [100000,64] f32
//
// R10: overlap scatter with copy. Flags are precomputed by two tiny
// dispatches; then ONE mega dispatch does both the update-scatter and the
// flag-skipped copy -- their write sets are disjoint (unique indices), so
// no ordering hazard, and the scatter's 52 MB hides under the copy's 460 MB.
//   1. zero_flags        (1 MB write)
//   2. flag_scatter      (0.4 MB read, 0.1 MB write)
//   3. mega: blocks [0,6250) scatter updates; blocks [6250,68750) skip-copy.

typedef float f32x4 __attribute__((ext_vector_type(4)));
typedef uint32_t u32x4 __attribute__((ext_vector_type(4)));

__global__ __launch_bounds__(256) void zero_flags_kernel(
    u32x4* __restrict__ p, size_t n16) {
    const size_t i = (size_t)blockIdx.x * blockDim.x + threadIdx.x;
    if (i < n16) p[i] = (u32x4){0u, 0u, 0u, 0u};
}

__global__ __launch_bounds__(256) void flag_scatter_kernel(
    const int* __restrict__ idx, uint8_t* __restrict__ flags, int n) {
    const int t = blockIdx.x * blockDim.x + threadIdx.x;
    if (t < n) flags[idx[t]] = 1;
}

__global__ __launch_bounds__(256) void mega_kernel(
    const f32x4* __restrict__ data,
    const f32x4* __restrict__ upd,
    const int* __restrict__ idx,
    const uint8_t* __restrict__ flags,
    f32x4* __restrict__ out,
    size_t total4,   // update float4 count (scatter segment)
    size_t n4) {     // out float4 count (copy segment)
    const size_t i = (size_t)blockIdx.x * blockDim.x + threadIdx.x;
    if (i < total4) {
        // Scatter segment: block-uniform branch (total4 is a multiple of 256).
        const size_t row = i >> 4;
        const size_t col = i & 15;
        const int r = idx[row];
        out[(size_t)r * 16 + col] = upd[i];
    } else {
        const size_t j = i - total4;
        if (j < n4 && !flags[j >> 4]) out[j] = data[j];
    }
}

// Fallback (ws too small): R8's plain flat copy + scatter.
__global__ __launch_bounds__(256) void copy_flat_kernel(
    const f32x4* __restrict__ src, f32x4* __restrict__ dst, size_t n4) {
    const size_t i = (size_t)blockIdx.x * blockDim.x + threadIdx.x;
    if (i < n4) dst[i] = src[i];
}

__global__ __launch_bounds__(256) void scatter_flat_kernel(
    const int* __restrict__ idx, const f32x4* __restrict__ upd,
    f32x4* __restrict__ out, size_t total4) {
    const size_t i = (size_t)blockIdx.x * blockDim.x + threadIdx.x;
    if (i < total4) {
        const size_t row = i >> 4;
        const size_t col = i & 15;
        const int r = idx[row];
        out[(size_t)r * 16 + col] = upd[i];
    }
}

extern "C" void kernel_launch(void* const* d_in, const int* in_sizes, int n_in,
                              void* d_out, int out_size, void* d_ws, size_t ws_size,
                              hipStream_t stream) {
    const float* data    = (const float*)d_in[0];
    const int*   indices = (const int*)d_in[1];
    const float* updates = (const float*)d_in[2];
    float* out = (float*)d_out;

    const size_t n4          = (size_t)out_size / 4;      // 16M float4
    const size_t num_rows    = (size_t)out_size / 64;     // 1,000,000
    const size_t num_updates = (size_t)in_sizes[2] / 64;  // 100,000
    const size_t total4      = num_updates * 16;          // 1.6M float4

    const int block = 256;
    auto blocks_for = [&](size_t work) {
        return (int)((work + block - 1) / block);
    };

    if (ws_size >= num_rows && (num_rows % 16) == 0 && (total4 % block) == 0) {
        uint8_t* flags = (uint8_t*)d_ws;
        const size_t n16 = num_rows / 16;
        zero_flags_kernel<<<blocks_for(n16), block, 0, stream>>>(
            (u32x4*)flags, n16);
        flag_scatter_kernel<<<blocks_for(num_updates), block, 0, stream>>>(
            indices, flags, (int)num_updates);
        mega_kernel<<<blocks_for(total4 + n4), block, 0, stream>>>(
            (const f32x4*)data, (const f32x4*)updates, indices, flags,
            (f32x4*)out, total4, n4);
    } else {
        copy_flat_kernel<<<blocks_for(n4), block, 0, stream>>>(
            (const f32x4*)data, (f32x4*)out, n4);
        scatter_flat_kernel<<<blocks_for(total4), block, 0, stream>>>(
            indices, (const f32x4*)updates, (f32x4*)out, total4);
    }
}